// Round 13
// baseline (1305.678 us; speedup 1.0000x reference)
//
#include <hip/hip_runtime.h>
#include <hip/hip_bf16.h>

// ---------------------------------------------------------------------------
// RecurrentBattleNet: 2-layer LSTM (B=512, T=256, IN=512, H=128) + FC head.
// Round 13: wave-specialized fused recurrence. R12 was correct but ran at
// 1 wave/SIMD (384 weight regs/lane) -> fully exposed latency chain
// (4460 cyc/step). Now 8 waves: waves 0-3 = layer 0 only (Wh0, 64 regs),
// waves 4-7 = layer 1 only (Wi1+Wh1, 128 regs) -> <=256 unified/wave ->
// 2 waves/SIMD; L1 MFMA phase overlaps L0 ew phase on separate pipes.
// Same dataflow as R12 (L1 lags one step); matched barrier counts per role.
// ---------------------------------------------------------------------------

#define BATCH 512
#define SEQT  256
#define INPUTD 512
#define HID   128
#define GATES 512   // 4*HID
#define RB    4     // batch rows per recurrence block

typedef __bf16 bf16_t;
typedef bf16_t bf16x4 __attribute__((ext_vector_type(4)));
typedef bf16_t bf16x8 __attribute__((ext_vector_type(8)));
typedef float  f32x4  __attribute__((ext_vector_type(4)));

__device__ __forceinline__ float sigm(float x) {
    return __builtin_amdgcn_rcpf(1.f + __expf(-x));
}
__device__ __forceinline__ float tanhfast(float x) {
    float xc = fminf(fmaxf(x, -15.f), 15.f);
    float e = __expf(2.f * xc);
    return (e - 1.f) * __builtin_amdgcn_rcpf(e + 1.f);
}

// ---------------------------------------------------------------------------
// fp32 -> bf16 conversion, vectorized (float4 in, bf16x4 out). n4 = n/4.
// ---------------------------------------------------------------------------
__global__ __launch_bounds__(256) void cvt_f32_bf16(
    const float* __restrict__ in, bf16_t* __restrict__ out, long n4)
{
    long i = (long)blockIdx.x * 256 + threadIdx.x;
    long stride = (long)gridDim.x * 256;
    for (; i < n4; i += stride) {
        float4 v = ((const float4*)in)[i];
        bf16x4 r;
        r[0] = (bf16_t)v.x; r[1] = (bf16_t)v.y;
        r[2] = (bf16_t)v.z; r[3] = (bf16_t)v.w;
        ((bf16x4*)out)[i] = r;
    }
}

// ---------------------------------------------------------------------------
// bf16 MFMA GEMM (layer-0 input projection) writing gate-major xp:
//   xp4[b>>2][t][gate][(b&3)*128 + hid]   (float)
// ---------------------------------------------------------------------------
__global__ __launch_bounds__(256) void gemm_mfma(
    const bf16_t* __restrict__ A, const bf16_t* __restrict__ W,
    const float* __restrict__ b1, const float* __restrict__ b2,
    float* __restrict__ out,
    int K, int tcs, int tcmask, int srcT, int t0)
{
    __shared__ bf16_t As[128 * 32];
    __shared__ bf16_t Bs[128 * 32];
    int tid = threadIdx.x;
    int l = tid & 63;
    int w = tid >> 6;
    int wm = w >> 1, wn = w & 1;
    int bn = blockIdx.x;
    int bm = blockIdx.y;
    int Tc = tcmask + 1;

    long aoff[2], boff[2];
    #pragma unroll
    for (int c = 0; c < 2; ++c) {
        int m = bm * 128 + (tid >> 2) + 64 * c;
        int xr = ((m >> tcs) * srcT) + t0 + (m & tcmask);
        aoff[c] = (long)xr * K + (tid & 3) * 8;
        int n = bn * 128 + (tid >> 2) + 64 * c;
        boff[c] = (long)n * K + (tid & 3) * 8;
    }

    f32x4 acc[4][4];
    #pragma unroll
    for (int i = 0; i < 4; ++i)
        #pragma unroll
        for (int j = 0; j < 4; ++j)
            acc[i][j] = (f32x4){0.f, 0.f, 0.f, 0.f};

    const int rbase = wm * 64 + (l & 15);
    const int cbase = wn * 64 + (l & 15);
    const int kfrag = (l >> 4) * 8;

    for (int kt = 0; kt < K; kt += 32) {
        __builtin_amdgcn_global_load_lds(
            (const __attribute__((address_space(1))) void*)(A + aoff[0] + kt),
            (__attribute__((address_space(3))) void*)(As + tid * 8), 16, 0, 0);
        __builtin_amdgcn_global_load_lds(
            (const __attribute__((address_space(1))) void*)(A + aoff[1] + kt),
            (__attribute__((address_space(3))) void*)(As + 2048 + tid * 8), 16, 0, 0);
        __builtin_amdgcn_global_load_lds(
            (const __attribute__((address_space(1))) void*)(W + boff[0] + kt),
            (__attribute__((address_space(3))) void*)(Bs + tid * 8), 16, 0, 0);
        __builtin_amdgcn_global_load_lds(
            (const __attribute__((address_space(1))) void*)(W + boff[1] + kt),
            (__attribute__((address_space(3))) void*)(Bs + 2048 + tid * 8), 16, 0, 0);
        __syncthreads();

        bf16x8 af[4], bfr[4];
        #pragma unroll
        for (int i = 0; i < 4; ++i)
            af[i] = *(const bf16x8*)(As + (rbase + i * 16) * 32 + kfrag);
        #pragma unroll
        for (int j = 0; j < 4; ++j)
            bfr[j] = *(const bf16x8*)(Bs + (cbase + j * 16) * 32 + kfrag);

        #pragma unroll
        for (int i = 0; i < 4; ++i)
            #pragma unroll
            for (int j = 0; j < 4; ++j)
                acc[i][j] = __builtin_amdgcn_mfma_f32_16x16x32_bf16(
                    af[i], bfr[j], acc[i][j], 0, 0, 0);
        __syncthreads();
    }

    #pragma unroll
    for (int i = 0; i < 4; ++i) {
        int m0 = bm * 128 + wm * 64 + i * 16 + (l >> 4) * 4;
        #pragma unroll
        for (int j = 0; j < 4; ++j) {
            int n = bn * 128 + wn * 64 + j * 16 + (l & 15);
            float bb = b1[n] + b2[n];
            int hid = n & 127;          // g == bn
            #pragma unroll
            for (int r = 0; r < 4; ++r) {
                int m = m0 + r;
                int b = m >> tcs;
                int t = m & tcmask;
                int br = b >> 2, brow = b & 3;
                out[(((long)br * Tc + t) * 4 + bn) * 512 + brow * 128 + hid] =
                    acc[i][j][r] + bb;
            }
        }
    }
}

// ---------------------------------------------------------------------------
// Wave-specialized fused two-layer LSTM recurrence.
// 512 thr / 8 waves. Waves 0-3: layer 0 (weights Wh0 in wA). Waves 4-7:
// layer 1 (wA=Wi1, wB=Wh1), lagging one step. Wave wl owns gate-cols
// {g*128 + wl*32 .. +32}. ew: thread handles units utid and utid+256 of
// its layer. 2 raw barriers per iteration, 2(Tc+1) total per wave.
// ---------------------------------------------------------------------------
#define BARRIER_()                                                             \
    do {                                                                       \
        asm volatile("s_waitcnt lgkmcnt(0)" ::: "memory");                     \
        __builtin_amdgcn_s_barrier();                                          \
        __builtin_amdgcn_sched_barrier(0);                                     \
    } while (0)

#define L0_STEP(XA, XB, kvar)                                                  \
    {                                                                          \
        bf16x8 a0[4];                                                          \
        _Pragma("unroll")                                                      \
        for (int ks = 0; ks < 4; ++ks) {                                       \
            int ba = (col * 256 + ks * 64 + lgroup * 16) ^ ((col & 7) << 4);   \
            a0[ks] = *(const bf16x8*)((const char*)h0_lds + ba);               \
        }                                                                      \
        _Pragma("unroll")                                                      \
        for (int c2 = 0; c2 < 2; ++c2) {                                       \
            f32x4 acc[4];                                                      \
            _Pragma("unroll")                                                  \
            for (int g = 0; g < 4; ++g) acc[g] = (f32x4){0.f, 0.f, 0.f, 0.f}; \
            _Pragma("unroll")                                                  \
            for (int ks = 0; ks < 4; ++ks)                                     \
                _Pragma("unroll")                                              \
                for (int g = 0; g < 4; ++g)                                    \
                    acc[g] = __builtin_amdgcn_mfma_f32_16x16x32_bf16(          \
                        a0[ks], __builtin_bit_cast(bf16x8, wA[c2][g][ks]),     \
                        acc[g], 0, 0, 0);                                      \
            if (lgroup == 0) {                                                 \
                _Pragma("unroll")                                              \
                for (int r = 0; r < 4; ++r) {                                  \
                    f32x4 v;                                                   \
                    v[0] = acc[0][r]; v[1] = acc[1][r];                        \
                    v[2] = acc[2][r]; v[3] = acc[3][r];                        \
                    *(f32x4*)((char*)g0_lds + r * 2048 +                       \
                              (wl * 32 + c2 * 16 + col) * 16) = v;             \
                }                                                              \
            }                                                                  \
        }                                                                      \
        BARRIER_();                                                            \
        {                                                                      \
            f32x4 gva = *(const f32x4*)((const char*)g0_lds + utid * 16);      \
            f32x4 gvb = *(const f32x4*)((const char*)g0_lds + utid * 16 + 4096);\
            float zi = gva[0] + XA.x, zf = gva[1] + XA.y;                      \
            float zg = gva[2] + XA.z, zo = gva[3] + XA.w;                      \
            ca = sigm(zf) * ca + sigm(zi) * tanhfast(zg);                      \
            ha = sigm(zo) * tanhfast(ca);                                      \
            *(bf16_t*)((char*)h0_lds + hba0) = (bf16_t)ha;                     \
            zi = gvb[0] + XB.x; zf = gvb[1] + XB.y;                            \
            zg = gvb[2] + XB.z; zo = gvb[3] + XB.w;                            \
            cb = sigm(zf) * cb + sigm(zi) * tanhfast(zg);                      \
            hb = sigm(zo) * tanhfast(cb);                                      \
            *(bf16_t*)((char*)h0_lds + hba1) = (bf16_t)hb;                     \
        }                                                                      \
        if (kvar + 2 < Tc) {                                                   \
            long o = (long)(kvar + 2) * 2048;                                  \
            XA.x = xpt[o];        XA.y = xpt[o + 512];                         \
            XA.z = xpt[o + 1024]; XA.w = xpt[o + 1536];                        \
            XB.x = xpt[o + 256];  XB.y = xpt[o + 768];                         \
            XB.z = xpt[o + 1280]; XB.w = xpt[o + 1792];                        \
        }                                                                      \
        BARRIER_();                                                            \
    }

__global__ __launch_bounds__(512, 2) void lstm_fused_ws(
    const float* __restrict__ xp4,   // [B/4][Tc][4][512] layer-0 projection
    const bf16_t* __restrict__ Wh0,  // Whh0 bf16 [512][128]
    const bf16_t* __restrict__ Wi1,  // Wih1 bf16 [512][128]
    const bf16_t* __restrict__ Wh1,  // Whh1 bf16 [512][128]
    const float* __restrict__ bih1, const float* __restrict__ bhh1,
    float* __restrict__ h0st, float* __restrict__ c0st,
    float* __restrict__ h1st, float* __restrict__ c1st,
    int Tc, int first)
{
    __shared__ __align__(16) bf16_t h0_lds[16 * HID];     // 4 KB, swizzled
    __shared__ __align__(16) bf16_t h1_lds[16 * HID];     // 4 KB, swizzled
    __shared__ __align__(16) float  g0_lds[4 * HID * 4];  // 8 KB
    __shared__ __align__(16) float  g1_lds[4 * HID * 4];  // 8 KB
    int tid = threadIdx.x;
    int l = tid & 63;
    int wv = tid >> 6;                // wave 0..7
    int isL1 = wv >= 4;
    int wl = wv & 3;                  // wave-within-role 0..3
    int utid = wl * 64 + l;           // 0..255 within role
    int r0 = blockIdx.x * RB;

    int col = l & 15;
    int lgroup = l >> 4;              // 0..3
    int kreg = lgroup * 8;            // B fragment k offset

    // role weights: L0 waves wA=Wh0 (wB dead); L1 waves wA=Wi1, wB=Wh1.
    // 128 f32x4-of-bf16x8 pinned to AGPR -> uniform 128 AGPR/wave.
    const bf16_t* srcA = isL1 ? Wi1 : Wh0;
    f32x4 wA[2][4][4], wB[2][4][4];
    #pragma unroll
    for (int c2 = 0; c2 < 2; ++c2)
        #pragma unroll
        for (int g = 0; g < 4; ++g)
            #pragma unroll
            for (int ks = 0; ks < 4; ++ks) {
                long o = (long)(g * 128 + wl * 32 + c2 * 16 + col) * HID
                         + ks * 32 + kreg;
                wA[c2][g][ks] = *(const f32x4*)(srcA + o);
                wB[c2][g][ks] = *(const f32x4*)(Wh1 + o);
            }
    #pragma unroll
    for (int c2 = 0; c2 < 2; ++c2)
        #pragma unroll
        for (int g = 0; g < 4; ++g)
            #pragma unroll
            for (int ks = 0; ks < 4; ++ks) {
                asm volatile("" : "+a"(wA[c2][g][ks]));
                asm volatile("" : "+a"(wB[c2][g][ks]));
            }

    // ew identity (within role): units utid (rows 0-1) and utid+256 (rows 2-3)
    int erow0 = utid >> 7;
    int erow1 = erow0 + 2;
    int ehid = utid & 127;
    const int hba0 = (erow0 * 256 + ehid * 2) ^ ((erow0 & 7) << 4);
    const int hba1 = (erow1 * 256 + ehid * 2) ^ ((erow1 & 7) << 4);

    const float* hsrc = isL1 ? h1st : h0st;
    const float* csrc = isL1 ? c1st : c0st;
    float ha = first ? 0.f : hsrc[(r0 + erow0) * HID + ehid];
    float ca = first ? 0.f : csrc[(r0 + erow0) * HID + ehid];
    float hb = first ? 0.f : hsrc[(r0 + erow1) * HID + ehid];
    float cb = first ? 0.f : csrc[(r0 + erow1) * HID + ehid];

    // zero h LDS (rows 4-15 stay zero), then stage role h rows swizzled
    if (tid < 256) ((f32x4*)h0_lds)[tid] = (f32x4){0.f, 0.f, 0.f, 0.f};
    else           ((f32x4*)h1_lds)[tid & 255] = (f32x4){0.f, 0.f, 0.f, 0.f};
    __syncthreads();
    {
        char* hstage = isL1 ? (char*)h1_lds : (char*)h0_lds;
        *(bf16_t*)(hstage + hba0) = (bf16_t)ha;
        *(bf16_t*)(hstage + hba1) = (bf16_t)hb;
    }
    __syncthreads();

    if (!isL1) {
        // ---------------- layer-0 waves ----------------
        const float* xpt = xp4 + (long)blockIdx.x * Tc * 2048 + utid;
        float4 xA, xB2;
        xA.x = xpt[0];    xA.y = xpt[512];
        xA.z = xpt[1024]; xA.w = xpt[1536];
        float4 xC, xD;
        xC.x = xpt[256];  xC.y = xpt[768];
        xC.z = xpt[1280]; xC.w = xpt[1792];
        if (Tc > 1) {
            xB2.x = xpt[2048];        xB2.y = xpt[2048 + 512];
            xB2.z = xpt[2048 + 1024]; xB2.w = xpt[2048 + 1536];
            xD.x = xpt[2048 + 256];   xD.y = xpt[2048 + 768];
            xD.z = xpt[2048 + 1280];  xD.w = xpt[2048 + 1792];
        } else {
            xB2 = make_float4(0.f, 0.f, 0.f, 0.f);
            xD = xB2;
        }

        for (int tt = 0; tt < Tc; tt += 2) {
            {
                L0_STEP(xA, xC, tt)
            }
            {
                L0_STEP(xB2, xD, (tt + 1))
            }
        }
        // L1's epilogue iteration (k = Tc): participate in barriers only
        BARRIER_();
        BARRIER_();

        h0st[(r0 + erow0) * HID + ehid] = ha;
        c0st[(r0 + erow0) * HID + ehid] = ca;
        h0st[(r0 + erow1) * HID + ehid] = hb;
        c0st[(r0 + erow1) * HID + ehid] = cb;
    } else {
        // ---------------- layer-1 waves ----------------
        float4 bias1;
        bias1.x = bih1[ehid]       + bhh1[ehid];
        bias1.y = bih1[128 + ehid] + bhh1[128 + ehid];
        bias1.z = bih1[256 + ehid] + bhh1[256 + ehid];
        bias1.w = bih1[384 + ehid] + bhh1[384 + ehid];

        // k = 0: no L1 work yet, barriers only
        BARRIER_();
        BARRIER_();

        for (int t1 = 0; t1 < Tc; ++t1) {
            // phase A: gates1[t1] = Wi1 @ h0[t1] + Wh1 @ h1[t1-1]
            bf16x8 a0[4], a1[4];
            #pragma unroll
            for (int ks = 0; ks < 4; ++ks) {
                int ba = (col * 256 + ks * 64 + lgroup * 16) ^ ((col & 7) << 4);
                a0[ks] = *(const bf16x8*)((const char*)h0_lds + ba);
                a1[ks] = *(const bf16x8*)((const char*)h1_lds + ba);
            }
            #pragma unroll
            for (int c2 = 0; c2 < 2; ++c2) {
                f32x4 acc[4];
                #pragma unroll
                for (int g = 0; g < 4; ++g)
                    acc[g] = (f32x4){0.f, 0.f, 0.f, 0.f};
                #pragma unroll
                for (int ks = 0; ks < 4; ++ks)
                    #pragma unroll
                    for (int g = 0; g < 4; ++g)
                        acc[g] = __builtin_amdgcn_mfma_f32_16x16x32_bf16(
                            a0[ks], __builtin_bit_cast(bf16x8, wA[c2][g][ks]),
                            acc[g], 0, 0, 0);
                #pragma unroll
                for (int ks = 0; ks < 4; ++ks)
                    #pragma unroll
                    for (int g = 0; g < 4; ++g)
                        acc[g] = __builtin_amdgcn_mfma_f32_16x16x32_bf16(
                            a1[ks], __builtin_bit_cast(bf16x8, wB[c2][g][ks]),
                            acc[g], 0, 0, 0);
                if (lgroup == 0) {
                    #pragma unroll
                    for (int r = 0; r < 4; ++r) {
                        f32x4 v;
                        v[0] = acc[0][r]; v[1] = acc[1][r];
                        v[2] = acc[2][r]; v[3] = acc[3][r];
                        *(f32x4*)((char*)g1_lds + r * 2048 +
                                  (wl * 32 + c2 * 16 + col) * 16) = v;
                    }
                }
            }
            BARRIER_();
            // phase B: ew update for units utid, utid+256
            {
                f32x4 gva = *(const f32x4*)((const char*)g1_lds + utid * 16);
                f32x4 gvb = *(const f32x4*)((const char*)g1_lds + utid * 16 + 4096);
                float zi = gva[0] + bias1.x, zf = gva[1] + bias1.y;
                float zg = gva[2] + bias1.z, zo = gva[3] + bias1.w;
                ca = sigm(zf) * ca + sigm(zi) * tanhfast(zg);
                ha = sigm(zo) * tanhfast(ca);
                *(bf16_t*)((char*)h1_lds + hba0) = (bf16_t)ha;
                zi = gvb[0] + bias1.x; zf = gvb[1] + bias1.y;
                zg = gvb[2] + bias1.z; zo = gvb[3] + bias1.w;
                cb = sigm(zf) * cb + sigm(zi) * tanhfast(zg);
                hb = sigm(zo) * tanhfast(cb);
                *(bf16_t*)((char*)h1_lds + hba1) = (bf16_t)hb;
            }
            BARRIER_();
        }

        h1st[(r0 + erow0) * HID + ehid] = ha;
        c1st[(r0 + erow0) * HID + ehid] = ca;
        h1st[(r0 + erow1) * HID + ehid] = hb;
        c1st[(r0 + erow1) * HID + ehid] = cb;
    }
}

// ---------------------------------------------------------------------------
// FC head + softmax + state copy-out. One block per batch row, 128 threads.
// out layout: probs [512*10] | h_n [2*512*128] | c_n [2*512*128]
// ---------------------------------------------------------------------------
__global__ __launch_bounds__(128) void fc_head(
    const float* __restrict__ h0st, const float* __restrict__ c0st,
    const float* __restrict__ h1st, const float* __restrict__ c1st,
    const float* __restrict__ fc1w, const float* __restrict__ fc1b,
    const float* __restrict__ fc2w, const float* __restrict__ fc2b,
    float* __restrict__ out)
{
    __shared__ float h1_s[HID];
    __shared__ float hid_s[64];
    __shared__ float log_s[10];
    int t = threadIdx.x;
    int b = blockIdx.x;

    h1_s[t] = h1st[b * HID + t];
    __syncthreads();

    if (t < 64) {
        float a = fc1b[t];
        const float* wrow = fc1w + t * HID;
        #pragma unroll 4
        for (int k = 0; k < HID; ++k) a = fmaf(wrow[k], h1_s[k], a);
        hid_s[t] = fmaxf(a, 0.f);
    }
    __syncthreads();

    if (t < 10) {
        float a = fc2b[t];
        const float* wrow = fc2w + t * 64;
        #pragma unroll 4
        for (int k = 0; k < 64; ++k) a = fmaf(wrow[k], hid_s[k], a);
        log_s[t] = a;
    }
    __syncthreads();

    if (t == 0) {
        float m = log_s[0];
        #pragma unroll
        for (int j = 1; j < 10; ++j) m = fmaxf(m, log_s[j]);
        float e[10];
        float s = 0.f;
        #pragma unroll
        for (int j = 0; j < 10; ++j) { e[j] = __expf(log_s[j] - m); s += e[j]; }
        float inv = __builtin_amdgcn_rcpf(s);
        #pragma unroll
        for (int j = 0; j < 10; ++j) out[b * 10 + j] = e[j] * inv;
    }

    float* hn = out + BATCH * 10;
    float* cn = hn + 2 * BATCH * HID;
    hn[b * HID + t] = h0st[b * HID + t];
    hn[BATCH * HID + b * HID + t] = h1_s[t];
    cn[b * HID + t] = c0st[b * HID + t];
    cn[BATCH * HID + b * HID + t] = c1st[b * HID + t];
}

// ---------------------------------------------------------------------------
extern "C" void kernel_launch(void* const* d_in, const int* in_sizes, int n_in,
                              void* d_out, int out_size, void* d_ws, size_t ws_size,
                              hipStream_t stream) {
    const float* x    = (const float*)d_in[0];
    const float* Wih0 = (const float*)d_in[1];
    const float* Whh0 = (const float*)d_in[2];
    const float* bih0 = (const float*)d_in[3];
    const float* bhh0 = (const float*)d_in[4];
    const float* Wih1 = (const float*)d_in[5];
    const float* Whh1 = (const float*)d_in[6];
    const float* bih1 = (const float*)d_in[7];
    const float* bhh1 = (const float*)d_in[8];
    const float* fc1w = (const float*)d_in[9];
    const float* fc1b = (const float*)d_in[10];
    const float* fc2w = (const float*)d_in[11];
    const float* fc2b = (const float*)d_in[12];
    float* out = (float*)d_out;

    int Tc = SEQT;
    while (Tc > 1) {
        size_t need = (size_t)BATCH * Tc * GATES * 4       // xp4
                    + (size_t)BATCH * SEQT * INPUTD * 2    // xb
                    + ((size_t)GATES * INPUTD + 3 * (size_t)GATES * HID) * 2
                    + 4 * (size_t)BATCH * HID * 4 + 256;
        if (need <= ws_size) break;
        Tc >>= 1;
    }
    int tcs = __builtin_ctz((unsigned)Tc);

    float*  xp   = (float*)d_ws;
    bf16_t* xb   = (bf16_t*)(xp + (size_t)BATCH * Tc * GATES);
    bf16_t* wb0  = xb + (size_t)BATCH * SEQT * INPUTD;
    bf16_t* wb1  = wb0 + (size_t)GATES * INPUTD;
    bf16_t* wh0b = wb1 + (size_t)GATES * HID;
    bf16_t* wh1b = wh0b + (size_t)GATES * HID;
    float*  h0st = (float*)(wh1b + (size_t)GATES * HID);
    float*  c0st = h0st + (size_t)BATCH * HID;
    float*  h1st = c0st + (size_t)BATCH * HID;
    float*  c1st = h1st + (size_t)BATCH * HID;

    cvt_f32_bf16<<<2048, 256, 0, stream>>>(x, xb, (long)BATCH * SEQT * INPUTD / 4);
    cvt_f32_bf16<<<256, 256, 0, stream>>>(Wih0, wb0, (long)GATES * INPUTD / 4);
    cvt_f32_bf16<<<64, 256, 0, stream>>>(Wih1, wb1, (long)GATES * HID / 4);
    cvt_f32_bf16<<<64, 256, 0, stream>>>(Whh0, wh0b, (long)GATES * HID / 4);
    cvt_f32_bf16<<<64, 256, 0, stream>>>(Whh1, wh1b, (long)GATES * HID / 4);

    int nchunk = SEQT / Tc;
    dim3 gemm_grid(GATES / 128, (BATCH * Tc) / 128);

    for (int ci = 0; ci < nchunk; ++ci) {
        int t0 = ci * Tc;
        gemm_mfma<<<gemm_grid, 256, 0, stream>>>(
            xb, wb0, bih0, bhh0, xp, INPUTD, tcs, Tc - 1, SEQT, t0);
        lstm_fused_ws<<<BATCH / RB, 512, 0, stream>>>(
            xp, wh0b, wb1, wh1b, bih1, bhh1,
            h0st, c0st, h1st, c1st, Tc, ci == 0);
    }

    fc_head<<<BATCH, 128, 0, stream>>>(
        h0st, c0st, h1st, c1st, fc1w, fc1b, fc2w, fc2b, out);
}

// Round 14
// 618.703 us; speedup vs baseline: 2.1103x; 2.1103x over previous
//
#include <hip/hip_runtime.h>
#include <hip/hip_bf16.h>

// ---------------------------------------------------------------------------
// RecurrentBattleNet: 2-layer LSTM (B=512, T=256, IN=512, H=128) + FC head.
// Round 14: producer-consumer DUAL-REC. One launch, 256 blocks:
//   blocks 0-127  : L0 recurrence (R9 shape: 8 waves x 16 cols, 64 AGPR/wave)
//                   + streams h0[t] to HBM pre-swizzled, posts flag per 16 steps.
//   blocks 128-255: L1 recurrence, Wi1@h0 inline (waves 0-3 pin Wi1, waves
//                   4-7 pin Wh1, 128 AGPR/wave; partials summed in ew), h0
//                   images DMA'd global->LDS with acquire-flag handshake.
// Both roles ~200 regs -> 2 waves/SIMD; 256 blocks = 256 CUs co-resident
// (1 block/CU at this reg count -> flag spin cannot deadlock).
// R10-R13 lesson: 8-wave blocks cap at 256 regs/wave; fused-all-weights
// needs >=320 -> must split across BLOCKS, not waves.
// ---------------------------------------------------------------------------

#define BATCH 512
#define SEQT  256
#define INPUTD 512
#define HID   128
#define GATES 512   // 4*HID
#define RB    4     // batch rows per recurrence block
#define SUBS  16    // producer->consumer flag granularity (steps)

typedef __bf16 bf16_t;
typedef bf16_t bf16x4 __attribute__((ext_vector_type(4)));
typedef bf16_t bf16x8 __attribute__((ext_vector_type(8)));
typedef float  f32x4  __attribute__((ext_vector_type(4)));

__device__ __forceinline__ float sigm(float x) {
    return __builtin_amdgcn_rcpf(1.f + __expf(-x));
}
__device__ __forceinline__ float tanhfast(float x) {
    float xc = fminf(fmaxf(x, -15.f), 15.f);
    float e = __expf(2.f * xc);
    return (e - 1.f) * __builtin_amdgcn_rcpf(e + 1.f);
}

// ---------------------------------------------------------------------------
// fp32 -> bf16 conversion, vectorized (float4 in, bf16x4 out). n4 = n/4.
// ---------------------------------------------------------------------------
__global__ __launch_bounds__(256) void cvt_f32_bf16(
    const float* __restrict__ in, bf16_t* __restrict__ out, long n4)
{
    long i = (long)blockIdx.x * 256 + threadIdx.x;
    long stride = (long)gridDim.x * 256;
    for (; i < n4; i += stride) {
        float4 v = ((const float4*)in)[i];
        bf16x4 r;
        r[0] = (bf16_t)v.x; r[1] = (bf16_t)v.y;
        r[2] = (bf16_t)v.z; r[3] = (bf16_t)v.w;
        ((bf16x4*)out)[i] = r;
    }
}

// ---------------------------------------------------------------------------
// bf16 MFMA GEMM (layer-0 input projection) writing gate-major xp:
//   xp4[b>>2][t][gate][(b&3)*128 + hid]   (float)
// ---------------------------------------------------------------------------
__global__ __launch_bounds__(256) void gemm_mfma(
    const bf16_t* __restrict__ A, const bf16_t* __restrict__ W,
    const float* __restrict__ b1, const float* __restrict__ b2,
    float* __restrict__ out,
    int K, int tcs, int tcmask, int srcT, int t0)
{
    __shared__ bf16_t As[128 * 32];
    __shared__ bf16_t Bs[128 * 32];
    int tid = threadIdx.x;
    int l = tid & 63;
    int w = tid >> 6;
    int wm = w >> 1, wn = w & 1;
    int bn = blockIdx.x;
    int bm = blockIdx.y;
    int Tc = tcmask + 1;

    long aoff[2], boff[2];
    #pragma unroll
    for (int c = 0; c < 2; ++c) {
        int m = bm * 128 + (tid >> 2) + 64 * c;
        int xr = ((m >> tcs) * srcT) + t0 + (m & tcmask);
        aoff[c] = (long)xr * K + (tid & 3) * 8;
        int n = bn * 128 + (tid >> 2) + 64 * c;
        boff[c] = (long)n * K + (tid & 3) * 8;
    }

    f32x4 acc[4][4];
    #pragma unroll
    for (int i = 0; i < 4; ++i)
        #pragma unroll
        for (int j = 0; j < 4; ++j)
            acc[i][j] = (f32x4){0.f, 0.f, 0.f, 0.f};

    const int rbase = wm * 64 + (l & 15);
    const int cbase = wn * 64 + (l & 15);
    const int kfrag = (l >> 4) * 8;

    for (int kt = 0; kt < K; kt += 32) {
        __builtin_amdgcn_global_load_lds(
            (const __attribute__((address_space(1))) void*)(A + aoff[0] + kt),
            (__attribute__((address_space(3))) void*)(As + tid * 8), 16, 0, 0);
        __builtin_amdgcn_global_load_lds(
            (const __attribute__((address_space(1))) void*)(A + aoff[1] + kt),
            (__attribute__((address_space(3))) void*)(As + 2048 + tid * 8), 16, 0, 0);
        __builtin_amdgcn_global_load_lds(
            (const __attribute__((address_space(1))) void*)(W + boff[0] + kt),
            (__attribute__((address_space(3))) void*)(Bs + tid * 8), 16, 0, 0);
        __builtin_amdgcn_global_load_lds(
            (const __attribute__((address_space(1))) void*)(W + boff[1] + kt),
            (__attribute__((address_space(3))) void*)(Bs + 2048 + tid * 8), 16, 0, 0);
        __syncthreads();

        bf16x8 af[4], bfr[4];
        #pragma unroll
        for (int i = 0; i < 4; ++i)
            af[i] = *(const bf16x8*)(As + (rbase + i * 16) * 32 + kfrag);
        #pragma unroll
        for (int j = 0; j < 4; ++j)
            bfr[j] = *(const bf16x8*)(Bs + (cbase + j * 16) * 32 + kfrag);

        #pragma unroll
        for (int i = 0; i < 4; ++i)
            #pragma unroll
            for (int j = 0; j < 4; ++j)
                acc[i][j] = __builtin_amdgcn_mfma_f32_16x16x32_bf16(
                    af[i], bfr[j], acc[i][j], 0, 0, 0);
        __syncthreads();
    }

    #pragma unroll
    for (int i = 0; i < 4; ++i) {
        int m0 = bm * 128 + wm * 64 + i * 16 + (l >> 4) * 4;
        #pragma unroll
        for (int j = 0; j < 4; ++j) {
            int n = bn * 128 + wn * 64 + j * 16 + (l & 15);
            float bb = b1[n] + b2[n];
            int hid = n & 127;          // g == bn
            #pragma unroll
            for (int r = 0; r < 4; ++r) {
                int m = m0 + r;
                int b = m >> tcs;
                int t = m & tcmask;
                int br = b >> 2, brow = b & 3;
                out[(((long)br * Tc + t) * 4 + bn) * 512 + brow * 128 + hid] =
                    acc[i][j][r] + bb;
            }
        }
    }
}

// ---------------------------------------------------------------------------
// Dual-role recurrence kernel. 256 blocks x 512 threads.
//   blocks 0-127  (pair = bid)     : layer-0 recurrence (producer)
//   blocks 128-255 (pair = bid-128): layer-1 recurrence (consumer)
// ---------------------------------------------------------------------------
#define BARRIER_()                                                             \
    do {                                                                       \
        asm volatile("s_waitcnt lgkmcnt(0)" ::: "memory");                     \
        __builtin_amdgcn_s_barrier();                                          \
        __builtin_amdgcn_sched_barrier(0);                                     \
    } while (0)

#define REC0_STEP(X, t)                                                        \
    {                                                                          \
        bf16x8 a[4];                                                           \
        _Pragma("unroll")                                                      \
        for (int ks = 0; ks < 4; ++ks) {                                       \
            int ba = (col * 256 + ks * 64 + lgroup * 16) ^ ((col & 7) << 4);   \
            a[ks] = *(const bf16x8*)((const char*)h_lds + ba);                 \
        }                                                                      \
        f32x4 acc[4];                                                          \
        _Pragma("unroll")                                                      \
        for (int g = 0; g < 4; ++g) acc[g] = (f32x4){0.f, 0.f, 0.f, 0.f};      \
        _Pragma("unroll")                                                      \
        for (int ks = 0; ks < 4; ++ks)                                         \
            _Pragma("unroll")                                                  \
            for (int g = 0; g < 4; ++g)                                        \
                acc[g] = __builtin_amdgcn_mfma_f32_16x16x32_bf16(              \
                    a[ks], __builtin_bit_cast(bf16x8, wreg[g][ks]), acc[g],    \
                    0, 0, 0);                                                  \
        if (lgroup == 0) {                                                     \
            _Pragma("unroll")                                                  \
            for (int r = 0; r < 4; ++r) {                                      \
                f32x4 v;                                                       \
                v[0] = acc[0][r]; v[1] = acc[1][r];                            \
                v[2] = acc[2][r]; v[3] = acc[3][r];                            \
                *(f32x4*)((char*)g_lds + r * 2048 + coff * 16) = v;            \
            }                                                                  \
        }                                                                      \
        BARRIER_();                                                            \
        {                                                                      \
            f32x4 gv = *(const f32x4*)((const char*)g_lds + tid * 16);         \
            float zi = gv[0] + X.x, zf = gv[1] + X.y;                          \
            float zg = gv[2] + X.z, zo = gv[3] + X.w;                          \
            c = sigm(zf) * c + sigm(zi) * tanhfast(zg);                        \
            h = sigm(zo) * tanhfast(c);                                        \
            *(bf16_t*)((char*)h_lds + hba) = (bf16_t)h;                        \
            h0qp[(long)(t) * 512] = (bf16_t)h;                                 \
        }                                                                      \
        if ((t) + 2 < Tc) {                                                    \
            long o = (long)((t) + 2) * 2048;                                   \
            X.x = xpt[o];        X.y = xpt[o + 512];                           \
            X.z = xpt[o + 1024]; X.w = xpt[o + 1536];                          \
        }                                                                      \
        if (((t) & (SUBS - 1)) == SUBS - 1)                                    \
            asm volatile("s_waitcnt vmcnt(0)" ::: "memory");                   \
        BARRIER_();                                                            \
        if ((((t) & (SUBS - 1)) == SUBS - 1) && tid == 0) {                    \
            __threadfence();                                                   \
            __hip_atomic_store(flagp + ((t) >> 4), 1u, __ATOMIC_RELEASE,       \
                               __HIP_MEMORY_SCOPE_AGENT);                      \
        }                                                                      \
    }

__global__ __launch_bounds__(512, 2) void lstm_dual(
    const float* __restrict__ xp4,   // [B/4][Tc][4][512] layer-0 projection
    const bf16_t* __restrict__ Wh0,  // Whh0 bf16 [512][128]
    const bf16_t* __restrict__ Wi1,  // Wih1 bf16 [512][128]
    const bf16_t* __restrict__ Wh1,  // Whh1 bf16 [512][128]
    const float* __restrict__ bih1, const float* __restrict__ bhh1,
    bf16_t* __restrict__ h0q,        // [128][Tc][512] swizzled h0 images
    unsigned* __restrict__ flags,    // [128][SEQT/SUBS]
    float* __restrict__ h0st, float* __restrict__ c0st,
    float* __restrict__ h1st, float* __restrict__ c1st,
    int Tc, int first, int subbase)
{
    __shared__ __align__(16) char pool[28 * 1024];
    int tid = threadIdx.x;
    int l = tid & 63;
    int wv = tid >> 6;                // wave 0..7
    int pair = blockIdx.x & 127;
    int r0 = pair * RB;
    int col = l & 15;
    int lgroup = l >> 4;              // 0..3
    int kreg = lgroup * 8;
    int erow = tid >> 7, ehid = tid & 127;
    const int hba = (erow * 256 + ehid * 2) ^ ((erow & 7) << 4);
    unsigned* flagp = flags + pair * (SEQT / SUBS) + subbase;

    if (blockIdx.x < 128) {
        // ================= producer: layer-0 recurrence =================
        bf16_t* h_lds = (bf16_t*)pool;           // 4 KB (16 rows, swizzled)
        float*  g_lds = (float*)(pool + 4096);   // 8 KB
        int coff = wv * 16 + col;                // owned gate-col

        f32x4 wreg[4][4];
        #pragma unroll
        for (int g = 0; g < 4; ++g)
            #pragma unroll
            for (int ks = 0; ks < 4; ++ks)
                wreg[g][ks] = *(const f32x4*)(Wh0 + (long)(g * 128 + coff) * HID
                                              + ks * 32 + kreg);
        #pragma unroll
        for (int g = 0; g < 4; ++g)
            #pragma unroll
            for (int ks = 0; ks < 4; ++ks)
                asm volatile("" : "+a"(wreg[g][ks]));

        float c = first ? 0.f : c0st[(r0 + erow) * HID + ehid];
        float h = first ? 0.f : h0st[(r0 + erow) * HID + ehid];

        ((float2*)h_lds)[tid & 255] = make_float2(0.f, 0.f);   // zero 4 KB
        __syncthreads();
        *(bf16_t*)((char*)h_lds + hba) = (bf16_t)h;
        __syncthreads();

        const float* xpt = xp4 + (long)pair * Tc * 2048 + tid;
        bf16_t* h0qp = h0q + (long)pair * Tc * 512 + (hba >> 1);
        float4 xA, xB;
        xA.x = xpt[0];    xA.y = xpt[512];
        xA.z = xpt[1024]; xA.w = xpt[1536];
        if (Tc > 1) {
            xB.x = xpt[2048];        xB.y = xpt[2048 + 512];
            xB.z = xpt[2048 + 1024]; xB.w = xpt[2048 + 1536];
        } else {
            xB = make_float4(0.f, 0.f, 0.f, 0.f);
        }

        for (int tt = 0; tt < Tc; tt += 2) {
            REC0_STEP(xA, tt)
            REC0_STEP(xB, tt + 1)
        }

        h0st[(r0 + erow) * HID + ehid] = h;
        c0st[(r0 + erow) * HID + ehid] = c;
    } else {
        // ================= consumer: layer-1 recurrence =================
        bf16_t* h0stg = (bf16_t*)pool;             // 2 x 4 KB images
        bf16_t* h1_lds = (bf16_t*)(pool + 8192);   // 4 KB
        float*  g1a = (float*)(pool + 12288);      // 8 KB (Wi1@h0 partial)
        float*  g1b = (float*)(pool + 20480);      // 8 KB (Wh1@h1 partial)
        int isWi = wv < 4;
        int w4 = wv & 3;                           // wave-within-role
        int coff1 = w4 * 32;                       // owned 32-col base

        const bf16_t* Wsrc = isWi ? Wi1 : Wh1;
        f32x4 wreg[2][4][4];
        #pragma unroll
        for (int c2 = 0; c2 < 2; ++c2)
            #pragma unroll
            for (int g = 0; g < 4; ++g)
                #pragma unroll
                for (int ks = 0; ks < 4; ++ks)
                    wreg[c2][g][ks] = *(const f32x4*)(
                        Wsrc + (long)(g * 128 + coff1 + c2 * 16 + col) * HID
                        + ks * 32 + kreg);
        #pragma unroll
        for (int c2 = 0; c2 < 2; ++c2)
            #pragma unroll
            for (int g = 0; g < 4; ++g)
                #pragma unroll
                for (int ks = 0; ks < 4; ++ks)
                    asm volatile("" : "+a"(wreg[c2][g][ks]));

        float4 bias1;
        bias1.x = bih1[ehid]       + bhh1[ehid];
        bias1.y = bih1[128 + ehid] + bhh1[128 + ehid];
        bias1.z = bih1[256 + ehid] + bhh1[256 + ehid];
        bias1.w = bih1[384 + ehid] + bhh1[384 + ehid];

        float c1 = first ? 0.f : c1st[(r0 + erow) * HID + ehid];
        float h1 = first ? 0.f : h1st[(r0 + erow) * HID + ehid];

        // zero h0stg (8 KB) + h1_lds (4 KB)
        ((float2*)pool)[tid] = make_float2(0.f, 0.f);
        ((float2*)pool)[tid + 512] = make_float2(0.f, 0.f);
        ((float2*)(pool + 8192))[tid & 255] = make_float2(0.f, 0.f);
        __syncthreads();
        *(bf16_t*)((char*)h1_lds + hba) = (bf16_t)h1;
        __syncthreads();

        // initial: wait chunk 0, DMA h0 image t=0 into h0stg[0]
        if (wv == 0) {
            while (__hip_atomic_load(flagp, __ATOMIC_ACQUIRE,
                                     __HIP_MEMORY_SCOPE_AGENT) == 0u)
                __builtin_amdgcn_s_sleep(2);
            __builtin_amdgcn_global_load_lds(
                (const __attribute__((address_space(1))) void*)(
                    h0q + (long)pair * Tc * 512 + l * 8),
                (__attribute__((address_space(3))) void*)h0stg, 16, 0, 0);
            asm volatile("s_waitcnt vmcnt(0)" ::: "memory");
        }
        __syncthreads();

        for (int t = 0; t < Tc; ++t) {
            int pw = (t + 1) & 3;        // prefetch-duty wave (a Wi-wave)
            if (t + 1 < Tc && wv == pw) {
                if (((t + 1) & (SUBS - 1)) == 0) {
                    unsigned* fp = flagp + ((t + 1) >> 4);
                    while (__hip_atomic_load(fp, __ATOMIC_ACQUIRE,
                                             __HIP_MEMORY_SCOPE_AGENT) == 0u)
                        __builtin_amdgcn_s_sleep(2);
                }
                __builtin_amdgcn_global_load_lds(
                    (const __attribute__((address_space(1))) void*)(
                        h0q + ((long)pair * Tc + t + 1) * 512 + l * 8),
                    (__attribute__((address_space(3))) void*)(
                        h0stg + ((t + 1) & 1) * 2048), 16, 0, 0);
            }

            // phase A: partial gates
            const char* asrc = isWi
                ? (const char*)(h0stg + (t & 1) * 2048)
                : (const char*)h1_lds;
            bf16x8 a[4];
            #pragma unroll
            for (int ks = 0; ks < 4; ++ks) {
                int ba = (col * 256 + ks * 64 + lgroup * 16) ^ ((col & 7) << 4);
                a[ks] = *(const bf16x8*)(asrc + ba);
            }
            float* gdst = isWi ? g1a : g1b;
            #pragma unroll
            for (int c2 = 0; c2 < 2; ++c2) {
                f32x4 acc[4];
                #pragma unroll
                for (int g = 0; g < 4; ++g) acc[g] = (f32x4){0.f, 0.f, 0.f, 0.f};
                #pragma unroll
                for (int ks = 0; ks < 4; ++ks)
                    #pragma unroll
                    for (int g = 0; g < 4; ++g)
                        acc[g] = __builtin_amdgcn_mfma_f32_16x16x32_bf16(
                            a[ks], __builtin_bit_cast(bf16x8, wreg[c2][g][ks]),
                            acc[g], 0, 0, 0);
                if (lgroup == 0) {
                    #pragma unroll
                    for (int r = 0; r < 4; ++r) {
                        f32x4 v;
                        v[0] = acc[0][r]; v[1] = acc[1][r];
                        v[2] = acc[2][r]; v[3] = acc[3][r];
                        *(f32x4*)((char*)gdst + r * 2048 +
                                  (coff1 + c2 * 16 + col) * 16) = v;
                    }
                }
            }
            BARRIER_();

            // phase B: ew (sum partials + bias)
            {
                f32x4 gva = *(const f32x4*)((const char*)g1a + tid * 16);
                f32x4 gvb = *(const f32x4*)((const char*)g1b + tid * 16);
                float zi = gva[0] + gvb[0] + bias1.x;
                float zf = gva[1] + gvb[1] + bias1.y;
                float zg = gva[2] + gvb[2] + bias1.z;
                float zo = gva[3] + gvb[3] + bias1.w;
                c1 = sigm(zf) * c1 + sigm(zi) * tanhfast(zg);
                h1 = sigm(zo) * tanhfast(c1);
                *(bf16_t*)((char*)h1_lds + hba) = (bf16_t)h1;
            }
            if (t + 1 < Tc && wv == pw)
                asm volatile("s_waitcnt vmcnt(0)" ::: "memory");
            BARRIER_();
        }

        h1st[(r0 + erow) * HID + ehid] = h1;
        c1st[(r0 + erow) * HID + ehid] = c1;
    }
}

// ---------------------------------------------------------------------------
// FC head + softmax + state copy-out. One block per batch row, 128 threads.
// out layout: probs [512*10] | h_n [2*512*128] | c_n [2*512*128]
// ---------------------------------------------------------------------------
__global__ __launch_bounds__(128) void fc_head(
    const float* __restrict__ h0st, const float* __restrict__ c0st,
    const float* __restrict__ h1st, const float* __restrict__ c1st,
    const float* __restrict__ fc1w, const float* __restrict__ fc1b,
    const float* __restrict__ fc2w, const float* __restrict__ fc2b,
    float* __restrict__ out)
{
    __shared__ float h1_s[HID];
    __shared__ float hid_s[64];
    __shared__ float log_s[10];
    int t = threadIdx.x;
    int b = blockIdx.x;

    h1_s[t] = h1st[b * HID + t];
    __syncthreads();

    if (t < 64) {
        float a = fc1b[t];
        const float* wrow = fc1w + t * HID;
        #pragma unroll 4
        for (int k = 0; k < HID; ++k) a = fmaf(wrow[k], h1_s[k], a);
        hid_s[t] = fmaxf(a, 0.f);
    }
    __syncthreads();

    if (t < 10) {
        float a = fc2b[t];
        const float* wrow = fc2w + t * 64;
        #pragma unroll 4
        for (int k = 0; k < 64; ++k) a = fmaf(wrow[k], hid_s[k], a);
        log_s[t] = a;
    }
    __syncthreads();

    if (t == 0) {
        float m = log_s[0];
        #pragma unroll
        for (int j = 1; j < 10; ++j) m = fmaxf(m, log_s[j]);
        float e[10];
        float s = 0.f;
        #pragma unroll
        for (int j = 0; j < 10; ++j) { e[j] = __expf(log_s[j] - m); s += e[j]; }
        float inv = __builtin_amdgcn_rcpf(s);
        #pragma unroll
        for (int j = 0; j < 10; ++j) out[b * 10 + j] = e[j] * inv;
    }

    float* hn = out + BATCH * 10;
    float* cn = hn + 2 * BATCH * HID;
    hn[b * HID + t] = h0st[b * HID + t];
    hn[BATCH * HID + b * HID + t] = h1_s[t];
    cn[b * HID + t] = c0st[b * HID + t];
    cn[BATCH * HID + b * HID + t] = c1st[b * HID + t];
}

// ---------------------------------------------------------------------------
extern "C" void kernel_launch(void* const* d_in, const int* in_sizes, int n_in,
                              void* d_out, int out_size, void* d_ws, size_t ws_size,
                              hipStream_t stream) {
    const float* x    = (const float*)d_in[0];
    const float* Wih0 = (const float*)d_in[1];
    const float* Whh0 = (const float*)d_in[2];
    const float* bih0 = (const float*)d_in[3];
    const float* bhh0 = (const float*)d_in[4];
    const float* Wih1 = (const float*)d_in[5];
    const float* Whh1 = (const float*)d_in[6];
    const float* bih1 = (const float*)d_in[7];
    const float* bhh1 = (const float*)d_in[8];
    const float* fc1w = (const float*)d_in[9];
    const float* fc1b = (const float*)d_in[10];
    const float* fc2w = (const float*)d_in[11];
    const float* fc2b = (const float*)d_in[12];
    float* out = (float*)d_out;

    int Tc = SEQT;
    while (Tc > SUBS) {
        size_t need = (size_t)BATCH * Tc * GATES * 4        // xp4
                    + (size_t)BATCH * SEQT * INPUTD * 2     // xb
                    + ((size_t)GATES * INPUTD + 3 * (size_t)GATES * HID) * 2
                    + (size_t)128 * Tc * 512 * 2            // h0q
                    + 4 * (size_t)BATCH * HID * 4
                    + 128 * (SEQT / SUBS) * 4 + 512;
        if (need <= ws_size) break;
        Tc >>= 1;
    }
    int tcs = __builtin_ctz((unsigned)Tc);

    float*    xp   = (float*)d_ws;
    bf16_t*   xb   = (bf16_t*)(xp + (size_t)BATCH * Tc * GATES);
    bf16_t*   wb0  = xb + (size_t)BATCH * SEQT * INPUTD;
    bf16_t*   wb1  = wb0 + (size_t)GATES * INPUTD;
    bf16_t*   wh0b = wb1 + (size_t)GATES * HID;
    bf16_t*   wh1b = wh0b + (size_t)GATES * HID;
    bf16_t*   h0q  = wh1b + (size_t)GATES * HID;
    float*    h0st = (float*)(h0q + (size_t)128 * Tc * 512);
    float*    c0st = h0st + (size_t)BATCH * HID;
    float*    h1st = c0st + (size_t)BATCH * HID;
    float*    c1st = h1st + (size_t)BATCH * HID;
    unsigned* flags = (unsigned*)(c1st + (size_t)BATCH * HID);

    // flags MUST be re-zeroed every call (graph replays don't re-poison)
    hipMemsetAsync(flags, 0, 128 * (SEQT / SUBS) * sizeof(unsigned), stream);

    cvt_f32_bf16<<<2048, 256, 0, stream>>>(x, xb, (long)BATCH * SEQT * INPUTD / 4);
    cvt_f32_bf16<<<256, 256, 0, stream>>>(Wih0, wb0, (long)GATES * INPUTD / 4);
    cvt_f32_bf16<<<64, 256, 0, stream>>>(Wih1, wb1, (long)GATES * HID / 4);
    cvt_f32_bf16<<<64, 256, 0, stream>>>(Whh0, wh0b, (long)GATES * HID / 4);
    cvt_f32_bf16<<<64, 256, 0, stream>>>(Whh1, wh1b, (long)GATES * HID / 4);

    int nchunk = SEQT / Tc;
    dim3 gemm_grid(GATES / 128, (BATCH * Tc) / 128);

    for (int ci = 0; ci < nchunk; ++ci) {
        gemm_mfma<<<gemm_grid, 256, 0, stream>>>(
            xb, wb0, bih0, bhh0, xp, INPUTD, tcs, Tc - 1, SEQT, ci * Tc);
        lstm_dual<<<256, 512, 0, stream>>>(
            xp, wh0b, wb1, wh1b, bih1, bhh1, h0q, flags,
            h0st, c0st, h1st, c1st, Tc, ci == 0, ci * (Tc / SUBS));
    }

    fc_head<<<BATCH, 128, 0, stream>>>(
        h0st, c0st, h1st, c1st, fc1w, fc1b, fc2w, fc2b, out);
}